// Round 12
// baseline (119.347 us; speedup 1.0000x reference)
//
#include <hip/hip_runtime.h>
#include <stdint.h>

typedef unsigned short u16;
typedef __attribute__((ext_vector_type(8))) short short8;
typedef __attribute__((ext_vector_type(4))) float f32x4;

#define MFMA16(a, b, c) __builtin_amdgcn_mfma_f32_16x16x32_bf16((a), (b), (c), 0, 0, 0)

__device__ __forceinline__ void gload16(const void* g, void* l) {
  __builtin_amdgcn_global_load_lds((const __attribute__((address_space(1))) void*)g,
                                   (__attribute__((address_space(3))) void*)l, 16, 0, 0);
}

__device__ __forceinline__ u16 bf16bits(float f) {
  union { float f; unsigned u; } x; x.f = f;
  unsigned r = x.u + 0x7fffu + ((x.u >> 16) & 1u);
  return (u16)(r >> 16);
}

__device__ __forceinline__ float bf16tof(u16 b) {
  union { unsigned u; float f; } x; x.u = ((unsigned)b) << 16;
  return x.f;
}

__device__ __forceinline__ float exp2fast(float x) {
  float r;
  asm("v_exp_f32 %0, %1" : "=v"(r) : "v"(x));
  return r;
}

// ---------------------------------------------------------------------------
// f32 -> bf16 conversion, 4 arrays in one launch (blockIdx.y selects array).
// ---------------------------------------------------------------------------
__global__ __launch_bounds__(256) void cvt4(const float* __restrict__ s0, u16* __restrict__ d0, int n0,
                                            const float* __restrict__ s1, u16* __restrict__ d1, int n1,
                                            const float* __restrict__ s2, u16* __restrict__ d2, int n2,
                                            const float* __restrict__ s3, u16* __restrict__ d3, int n3) {
  const float* s; u16* d; int n;
  switch (blockIdx.y) {
    case 0:  s = s0; d = d0; n = n0; break;
    case 1:  s = s1; d = d1; n = n1; break;
    case 2:  s = s2; d = d2; n = n2; break;
    default: s = s3; d = d3; n = n3; break;
  }
  int stride = gridDim.x * blockDim.x;
  for (int i = blockIdx.x * blockDim.x + threadIdx.x; i * 8 < n; i += stride) {
    float4 a = ((const float4*)s)[i * 2];
    float4 b = ((const float4*)s)[i * 2 + 1];
    union { u16 u[8]; uint4 v; } pk;
    pk.u[0] = bf16bits(a.x); pk.u[1] = bf16bits(a.y);
    pk.u[2] = bf16bits(a.z); pk.u[3] = bf16bits(a.w);
    pk.u[4] = bf16bits(b.x); pk.u[5] = bf16bits(b.y);
    pk.u[6] = bf16bits(b.z); pk.u[7] = bf16bits(b.w);
    ((uint4*)d)[i] = pk.v;
  }
}

// ---------------------------------------------------------------------------
// GEMM: C[M,N] = A[M,K] @ B[N,K]^T   (bf16 in, K contiguous — "BT" layout)
// BM=128, BN=128, BK=32. 8 waves in 2x4; wave tile 64x32 (acc[4][2]) —
// per-wave code identical to the proven BN=64 version. 1 A-gload + 1
// B-gload per thread per K-step. Grid (N/128, M/128).
// EPI=0: f32 store to outf.  EPI=1: dual bf16 store q_td / q_dt.
// ---------------------------------------------------------------------------
template <int EPI>
__global__ __launch_bounds__(512) void gemm_bt(const u16* __restrict__ A,
                                               const u16* __restrict__ Bw,
                                               u16* __restrict__ out0,
                                               u16* __restrict__ out1,
                                               float* __restrict__ outf,
                                               int M, int N, int K) {
  __shared__ __align__(16) char smem[2 * 16384];  // per buf: A 8192 + B 8192
  const int tid = threadIdx.x;
  const int lane = tid & 63, w = tid >> 6;   // w in [0,8)
  const int g = lane >> 4, l15 = lane & 15;
  const int m0 = blockIdx.y * 128, n0 = blockIdx.x * 128;
  const int wm = w >> 2, wn = w & 3;
  const int NK = K >> 5;
  f32x4 acc[4][2] = {};

  auto stage = [&](int kk, int buf) {
    char* Ab_l = smem + buf * 16384;
    char* Bb_l = smem + buf * 16384 + 8192;
    int row = w * 16 + (lane >> 2);          // 0..127
    const char* Ab = (const char*)A + ((size_t)m0 * K + kk * 32) * 2;
    gload16(Ab + (size_t)row * (K * 2) + (lane & 3) * 16, Ab_l + w * 1024);
    const char* Bb = (const char*)Bw + ((size_t)n0 * K + kk * 32) * 2;
    gload16(Bb + (size_t)row * (K * 2) + (lane & 3) * 16, Bb_l + w * 1024);
  };

  stage(0, 0);
  __syncthreads();
  for (int kk = 0; kk < NK; ++kk) {
    int buf = kk & 1;
    if (kk + 1 < NK) stage(kk + 1, buf ^ 1);
    const char* Abuf = smem + buf * 16384;
    const char* Bbuf = Abuf + 8192;
    short8 af[4], bfr[2];
#pragma unroll
    for (int mt = 0; mt < 4; ++mt)
      af[mt] = *(const short8*)(Abuf + (wm * 64 + mt * 16 + l15) * 64 + g * 16);
#pragma unroll
    for (int nt = 0; nt < 2; ++nt)
      bfr[nt] = *(const short8*)(Bbuf + (wn * 32 + nt * 16 + l15) * 64 + g * 16);
#pragma unroll
    for (int mt = 0; mt < 4; ++mt)
#pragma unroll
      for (int nt = 0; nt < 2; ++nt)
        acc[mt][nt] = MFMA16(af[mt], bfr[nt], acc[mt][nt]);
    __syncthreads();
  }

#pragma unroll
  for (int mt = 0; mt < 4; ++mt)
#pragma unroll
    for (int nt = 0; nt < 2; ++nt) {
      int n = n0 + wn * 32 + nt * 16 + l15;
      int mbase = m0 + wm * 64 + mt * 16 + 4 * g;
      if constexpr (EPI == 0) {
#pragma unroll
        for (int r = 0; r < 4; ++r)
          outf[(size_t)(mbase + r) * N + n] = acc[mt][nt][r];
      } else {
        int b = mbase >> 11, t = mbase & 2047;
        int h = n >> 6, d = n & 63;
        size_t bhb = (size_t)(b * 16 + h) * (2048 * 64);
        union { u16 u[4]; uint2 v; } pk;
#pragma unroll
        for (int r = 0; r < 4; ++r) {
          u16 uu = bf16bits(acc[mt][nt][r]);
          out0[bhb + (size_t)(t + r) * 64 + d] = uu;  // [B,H,T,64]
          pk.u[r] = uu;
        }
        *(uint2*)(out1 + bhb + (size_t)d * 2048 + t) = pk.v;  // [B,H,64,T]
      }
    }
}

// ---------------------------------------------------------------------------
// Flash attention with relative-position bias. K=V=Q (bf16).
// VERBATIM round-6 passing kernel. Swapped QK^T (A=K, B=Q); lane holds
// P[q=l15][k=16jt+4g+r]; P via per-wave XOR-swizzled LDS buffer (4x b64
// writes per tile); no-max exp2 softmax; row sums in-register.
// ---------------------------------------------------------------------------
__global__ __launch_bounds__(256) void attn_rel(const u16* __restrict__ qtd,
                                                const u16* __restrict__ qdt,
                                                const u16* __restrict__ relk,
                                                u16* __restrict__ outa) {
  // LDS: [0,32768) K/V double buffers (K 8KB + VT 8KB per buf)
  //      [0,10240) aliased: rel_k_emb padded to [80][64] bf16 (prologue only)
  //      [32768,40960) qrel [64][64] bf16 (rel 0..63; rel=64 kept in bhi reg)
  //      [40960,49152) P per-wave [16][128B] bf16, XOR-swizzled
  __shared__ __align__(16) char smem[49152];
  const int tid = threadIdx.x;
  const int lane = tid & 63, w = tid >> 6;
  const int g = lane >> 4, l15 = lane & 15;
  // XCD-aware remap: lin%8 = XCD; 4 consecutive bh per XCD (K/V fits 4MB L2).
  int lin = blockIdx.y * 32 + blockIdx.x;
  int sidx = lin >> 3;
  const int bh = (lin & 7) * 4 + (sidx & 3);
  const int q0 = (sidx >> 2) * 64;
  const int q0w = q0 + w * 16;
  u16* qrelb = (u16*)(smem + 32768);
  char* Pbuf = smem + 40960 + w * 2048;

  // Q fragments (B-operand): row q = l15, d = g*8 (+32c); prescale SCALE*log2e
  short8 qa[2];
  {
    size_t rowoff = ((size_t)bh * 2048 + q0w + l15) * 64;
    qa[0] = *(const short8*)(qtd + rowoff + g * 8);
    qa[1] = *(const short8*)(qtd + rowoff + g * 8 + 32);
    const float QS = 0.18033688f;  // 0.125 * log2(e)
#pragma unroll
    for (int c = 0; c < 2; ++c)
#pragma unroll
      for (int e = 0; e < 8; ++e)
        qa[c][e] = (short)bf16bits(bf16tof((u16)qa[c][e]) * QS);
  }

  // Stage rel_k_emb (65x64 bf16 = 520 chunks), zero-pad rows 65..79
  for (int c = tid; c < 520; c += 256)
    *(uint4*)(smem + c * 16) = *(const uint4*)((const char*)relk + c * 16);
  for (int c = 520 + tid; c < 640; c += 256) {
    uint4 z; z.x = 0u; z.y = 0u; z.z = 0u; z.w = 0u;
    *(uint4*)(smem + c * 16) = z;
  }
  __syncthreads();

  // qrel (swapped): aq[t] = D[rel=t*16+4g+r][q=l15]
  f32x4 aq[5] = {};
#pragma unroll
  for (int t = 0; t < 5; ++t)
#pragma unroll
    for (int c = 0; c < 2; ++c) {
      short8 rb = *(const short8*)(smem + ((t * 16 + l15) * 64 + g * 8 + c * 32) * 2);
      aq[t] = MFMA16(rb, qa[c], aq[t]);
    }
  // per-lane bias for own q-row l15: rel=64 at (g=0, reg 0, col=l15) of aq[4];
  // rel=0 at same coords of aq[0].
  float bhi = __shfl(aq[4][0], l15);
  float blo = __shfl(aq[0][0], l15);
  // store rel 0..63 into qrelb[q][rel]  (q row-in-block = w*16+l15)
#pragma unroll
  for (int t = 0; t < 4; ++t)
#pragma unroll
    for (int r = 0; r < 4; ++r)
      qrelb[(w * 16 + l15) * 64 + t * 16 + 4 * g + r] = bf16bits(aq[t][r]);
  __syncthreads();  // rel region reads done before K staging overwrites it

  auto stageKV = [&](int kv0, int buf) {
    char* Kb = smem + buf * 16384;
    char* Vb = Kb + 8192;
    int sub = lane >> 3, chunk = lane & 7;
#pragma unroll
    for (int i = 0; i < 2; ++i) {
      int rloc = (w * 2 + i) * 8 + sub;  // 0..63 ; rloc&7 == sub
      int swz = (chunk * 16) ^ ((rloc & 7) << 4);
      gload16((const char*)qtd + ((size_t)bh * 2048 + kv0 + rloc) * 128 + swz,
              Kb + (w * 2 + i) * 1024);
      gload16((const char*)qdt + ((size_t)bh * 64 + rloc) * 4096 + kv0 * 2 + swz,
              Vb + (w * 2 + i) * 1024);
    }
  };

  f32x4 aco[4] = {};
  float lrow = 0.f;  // partial row-sum for q = l15 (own k-slices)

  stageKV(0, 0);
  __syncthreads();
  for (int ti = 0; ti < 32; ++ti) {
    int buf = ti & 1;
    int kv0 = ti * 64;
    if (ti + 1 < 32) stageKV(kv0 + 64, buf ^ 1);
    const char* Kb = smem + buf * 16384;
    const char* Vb = Kb + 8192;

    // bias as accumulator init; s layout D[k=jt*16+4g+r][q=l15]
    f32x4 s[4];
    bool farL = (q0w - (kv0 + 63)) >= 32;   // all i-j >= 32  -> bhi
    bool farR = (q0w + 15 - kv0) <= -32;    // all i-j <= -32 -> blo
    if (farL || farR) {
      float bv = farL ? bhi : blo;
      f32x4 binit = {bv, bv, bv, bv};
#pragma unroll
      for (int jt = 0; jt < 4; ++jt) s[jt] = binit;
    } else {
#pragma unroll
      for (int jt = 0; jt < 4; ++jt)
#pragma unroll
        for (int r = 0; r < 4; ++r) {
          int dd = (q0w + l15) - (kv0 + jt * 16 + 4 * g + r);
          int idx = dd < -32 ? 0 : (dd > 31 ? 63 : dd + 32);
          float tb = bf16tof(qrelb[(w * 16 + l15) * 64 + idx]);
          s[jt][r] = dd >= 32 ? bhi : tb;
        }
    }

    // S^T = K Q^T + bias  (Q carries SCALE*log2e)
#pragma unroll
    for (int jt = 0; jt < 4; ++jt) {
      int jloc = jt * 16 + l15;
      int sw = (jloc & 7) << 4;
#pragma unroll
      for (int c = 0; c < 2; ++c) {
        short8 kb = *(const short8*)(Kb + ((jloc * 128 + g * 16 + c * 64) ^ sw));
        s[jt] = MFMA16(kb, qa[c], s[jt]);
      }
    }

    // P = 2^S (unnormalized); lane owns q=l15, k = jt*16+4g+r
    // store P[q][k] to per-wave swizzled Pbuf: one b64 per jt
    float lsum = 0.f;
    int psw = (l15 & 7) << 4;
#pragma unroll
    for (int jt = 0; jt < 4; ++jt) {
      float p0 = exp2fast(s[jt][0]);
      float p1 = exp2fast(s[jt][1]);
      float p2 = exp2fast(s[jt][2]);
      float p3 = exp2fast(s[jt][3]);
      lsum += (p0 + p1) + (p2 + p3);
      union { float f; unsigned u; } c0, c1, c2, c3;
      c0.f = p0; c1.f = p1; c2.f = p2; c3.f = p3;
      uint2 wv;
      wv.x = (c0.u >> 16) | (c1.u & 0xFFFF0000u);
      wv.y = (c2.u >> 16) | (c3.u & 0xFFFF0000u);
      *(uint2*)(Pbuf + ((l15 * 128 + jt * 32 + g * 8) ^ psw)) = wv;
    }
    lrow += lsum;

    // O += P V   (A = P rows from Pbuf; B = V^T tile)
    short8 pa0 = *(const short8*)(Pbuf + ((l15 * 128 + g * 16) ^ psw));
    short8 pa1 = *(const short8*)(Pbuf + ((l15 * 128 + g * 16 + 64) ^ psw));
#pragma unroll
    for (int dt = 0; dt < 4; ++dt) {
      int dloc = dt * 16 + l15;
      int sw = (dloc & 7) << 4;
      short8 vb0 = *(const short8*)(Vb + ((dloc * 128 + g * 16) ^ sw));
      short8 vb1 = *(const short8*)(Vb + ((dloc * 128 + g * 16 + 64) ^ sw));
      aco[dt] = MFMA16(pa0, vb0, aco[dt]);
      aco[dt] = MFMA16(pa1, vb1, aco[dt]);
    }
    __syncthreads();
  }

  // finish row sums: reduce partials across the 4 g-lanes of each l15
  lrow += __shfl_xor(lrow, 16);
  lrow += __shfl_xor(lrow, 32);

  // epilogue: O/l -> [B,T,H,64]   (aco: q=4g+r, d=l15+16dt)
  int b = bh >> 4, h = bh & 15;
#pragma unroll
  for (int r = 0; r < 4; ++r) {
    float lr = __shfl(lrow, 4 * g + r);  // lanes 0..15 hold l(q=l15)
    float rl = 1.0f / lr;
    int t = q0w + 4 * g + r;
    size_t base = ((size_t)(b * 2048 + t) * 16 + h) * 64;
#pragma unroll
    for (int dt = 0; dt < 4; ++dt)
      outa[base + dt * 16 + l15] = bf16bits(aco[dt][r] * rl);
  }
}

// ---------------------------------------------------------------------------
extern "C" void kernel_launch(void* const* d_in, const int* in_sizes, int n_in,
                              void* d_out, int out_size, void* d_ws, size_t ws_size,
                              hipStream_t stream) {
  const float* x    = (const float*)d_in[0];   // [2,2048,1024] f32
  const float* Wq   = (const float*)d_in[1];   // [1024,1024] f32
  const float* Wo   = (const float*)d_in[2];   // [1024,1024] f32
  const float* relk = (const float*)d_in[3];   // [65,64] f32
  float* out = (float*)d_out;                  // [2,2048,1024] f32

  u16* q_td   = (u16*)d_ws;                    // 4,194,304  [B,H,T,64] bf16
  u16* q_dt   = q_td + 4194304;                // 4,194,304  [B,H,64,T] bf16
  u16* x_bf   = q_dt + 4194304;                // 4,194,304  (aliased as attn later)
  u16* wq_bf  = x_bf + 4194304;                // 1,048,576
  u16* wo_bf  = wq_bf + 1048576;               // 1,048,576
  u16* rel_bf = wo_bf + 1048576;               // 4,160
  u16* attn   = x_bf;                          // alias: x_bf consumed by gemm1

  // 1) f32 -> bf16 for all inputs
  cvt4<<<dim3(2048, 4), 256, 0, stream>>>(x, x_bf, 4194304,
                                          Wq, wq_bf, 1048576,
                                          Wo, wo_bf, 1048576,
                                          relk, rel_bf, 4160);
  // 2) q = x @ Wq^T  (dual-layout bf16 store; 128x128 tiles, 8 waves)
  gemm_bt<1><<<dim3(8, 32), 512, 0, stream>>>(x_bf, wq_bf, q_td, q_dt, nullptr,
                                              4096, 1024, 1024);
  // 3) flash attention with relative bias (verbatim round-6 passing kernel)
  attn_rel<<<dim3(32, 32), 256, 0, stream>>>(q_td, q_dt, rel_bf, attn);
  // 4) out = attn @ Wo^T  (f32 store; 128x128 tiles, 8 waves)
  gemm_bt<0><<<dim3(8, 32), 512, 0, stream>>>(attn, wo_bf, nullptr, nullptr, out,
                                              4096, 1024, 1024);
}

// Round 13
// 115.466 us; speedup vs baseline: 1.0336x; 1.0336x over previous
//
#include <hip/hip_runtime.h>
#include <stdint.h>

typedef unsigned short u16;
typedef __attribute__((ext_vector_type(8))) short short8;
typedef __attribute__((ext_vector_type(4))) float f32x4;

#define MFMA16(a, b, c) __builtin_amdgcn_mfma_f32_16x16x32_bf16((a), (b), (c), 0, 0, 0)

__device__ __forceinline__ void gload16(const void* g, void* l) {
  __builtin_amdgcn_global_load_lds((const __attribute__((address_space(1))) void*)g,
                                   (__attribute__((address_space(3))) void*)l, 16, 0, 0);
}

__device__ __forceinline__ u16 bf16bits(float f) {
  union { float f; unsigned u; } x; x.f = f;
  unsigned r = x.u + 0x7fffu + ((x.u >> 16) & 1u);
  return (u16)(r >> 16);
}

__device__ __forceinline__ float bf16tof(u16 b) {
  union { unsigned u; float f; } x; x.u = ((unsigned)b) << 16;
  return x.f;
}

__device__ __forceinline__ float exp2fast(float x) {
  float r;
  asm("v_exp_f32 %0, %1" : "=v"(r) : "v"(x));
  return r;
}

// ---------------------------------------------------------------------------
// f32 -> bf16 conversion, 4 arrays in one launch (blockIdx.y selects array).
// ---------------------------------------------------------------------------
__global__ __launch_bounds__(256) void cvt4(const float* __restrict__ s0, u16* __restrict__ d0, int n0,
                                            const float* __restrict__ s1, u16* __restrict__ d1, int n1,
                                            const float* __restrict__ s2, u16* __restrict__ d2, int n2,
                                            const float* __restrict__ s3, u16* __restrict__ d3, int n3) {
  const float* s; u16* d; int n;
  switch (blockIdx.y) {
    case 0:  s = s0; d = d0; n = n0; break;
    case 1:  s = s1; d = d1; n = n1; break;
    case 2:  s = s2; d = d2; n = n2; break;
    default: s = s3; d = d3; n = n3; break;
  }
  int stride = gridDim.x * blockDim.x;
  for (int i = blockIdx.x * blockDim.x + threadIdx.x; i * 8 < n; i += stride) {
    float4 a = ((const float4*)s)[i * 2];
    float4 b = ((const float4*)s)[i * 2 + 1];
    union { u16 u[8]; uint4 v; } pk;
    pk.u[0] = bf16bits(a.x); pk.u[1] = bf16bits(a.y);
    pk.u[2] = bf16bits(a.z); pk.u[3] = bf16bits(a.w);
    pk.u[4] = bf16bits(b.x); pk.u[5] = bf16bits(b.y);
    pk.u[6] = bf16bits(b.z); pk.u[7] = bf16bits(b.w);
    ((uint4*)d)[i] = pk.v;
  }
}

// ---------------------------------------------------------------------------
// GEMM: C[M,N] = A[M,K] @ B[N,K]^T   (bf16 in, K contiguous — "BT" layout)
// BM=128, BN=128, BK=64. 8 waves in 2x4; wave tile 64x32 (acc[4][2]).
// LDS rows are 128B (the G4 conflict shape) -> attn-proven XOR swizzle:
// linear gload_lds dest, inverse-swizzled global source, XOR on read.
// Grid (N/128, M/128).  EPI=0: f32 store.  EPI=1: dual bf16 store.
// ---------------------------------------------------------------------------
template <int EPI>
__global__ __launch_bounds__(512) void gemm_bt(const u16* __restrict__ A,
                                               const u16* __restrict__ Bw,
                                               u16* __restrict__ out0,
                                               u16* __restrict__ out1,
                                               float* __restrict__ outf,
                                               int M, int N, int K) {
  __shared__ __align__(16) char smem[2 * 32768];  // per buf: A 16K + B 16K
  const int tid = threadIdx.x;
  const int lane = tid & 63, w = tid >> 6;   // w in [0,8)
  const int g = lane >> 4, l15 = lane & 15;
  const int m0 = blockIdx.y * 128, n0 = blockIdx.x * 128;
  const int wm = w >> 2, wn = w & 3;
  const int NK = K >> 6;
  const size_t K2 = (size_t)K * 2;
  f32x4 acc[4][2] = {};

  auto stage = [&](int kk, int buf) {
    char* Ab_l = smem + buf * 32768;
    char* Bb_l = smem + buf * 32768 + 16384;
    int sub = lane >> 3, chunk = lane & 7;
    const char* Ab = (const char*)A + ((size_t)m0 * K + kk * 64) * 2;
    const char* Bb = (const char*)Bw + ((size_t)n0 * K + kk * 64) * 2;
#pragma unroll
    for (int i = 0; i < 2; ++i) {
      int row = i * 64 + w * 8 + sub;              // 0..127 ; row&7 == sub
      int swz = (chunk * 16) ^ ((row & 7) << 4);   // inverse-swizzled source
      gload16(Ab + (size_t)row * K2 + swz, Ab_l + i * 8192 + w * 1024);
      gload16(Bb + (size_t)row * K2 + swz, Bb_l + i * 8192 + w * 1024);
    }
  };

  stage(0, 0);
  __syncthreads();
  for (int kk = 0; kk < NK; ++kk) {
    int buf = kk & 1;
    if (kk + 1 < NK) stage(kk + 1, buf ^ 1);
    const char* Abuf = smem + buf * 32768;
    const char* Bbuf = Abuf + 16384;
    int sw = (l15 & 7) << 4;
    short8 af[4][2], bfr[2][2];
#pragma unroll
    for (int mt = 0; mt < 4; ++mt) {
      int row = wm * 64 + mt * 16 + l15;
#pragma unroll
      for (int c = 0; c < 2; ++c)
        af[mt][c] = *(const short8*)(Abuf + ((row * 128 + g * 16 + c * 64) ^ sw));
    }
#pragma unroll
    for (int nt = 0; nt < 2; ++nt) {
      int row = wn * 32 + nt * 16 + l15;
#pragma unroll
      for (int c = 0; c < 2; ++c)
        bfr[nt][c] = *(const short8*)(Bbuf + ((row * 128 + g * 16 + c * 64) ^ sw));
    }
#pragma unroll
    for (int c = 0; c < 2; ++c)
#pragma unroll
      for (int mt = 0; mt < 4; ++mt)
#pragma unroll
        for (int nt = 0; nt < 2; ++nt)
          acc[mt][nt] = MFMA16(af[mt][c], bfr[nt][c], acc[mt][nt]);
    __syncthreads();
  }

#pragma unroll
  for (int mt = 0; mt < 4; ++mt)
#pragma unroll
    for (int nt = 0; nt < 2; ++nt) {
      int n = n0 + wn * 32 + nt * 16 + l15;
      int mbase = m0 + wm * 64 + mt * 16 + 4 * g;
      if constexpr (EPI == 0) {
#pragma unroll
        for (int r = 0; r < 4; ++r)
          outf[(size_t)(mbase + r) * N + n] = acc[mt][nt][r];
      } else {
        int b = mbase >> 11, t = mbase & 2047;
        int h = n >> 6, d = n & 63;
        size_t bhb = (size_t)(b * 16 + h) * (2048 * 64);
        union { u16 u[4]; uint2 v; } pk;
#pragma unroll
        for (int r = 0; r < 4; ++r) {
          u16 uu = bf16bits(acc[mt][nt][r]);
          out0[bhb + (size_t)(t + r) * 64 + d] = uu;  // [B,H,T,64]
          pk.u[r] = uu;
        }
        *(uint2*)(out1 + bhb + (size_t)d * 2048 + t) = pk.v;  // [B,H,64,T]
      }
    }
}

// ---------------------------------------------------------------------------
// Flash attention with relative-position bias. K=V=Q (bf16).
// VERBATIM round-6 passing kernel (FROZEN — 5 structurally-equivalent edits
// failed; do not modify). Swapped QK^T (A=K, B=Q); lane holds
// P[q=l15][k=16jt+4g+r]; P via per-wave XOR-swizzled LDS buffer; no-max
// exp2 softmax; row sums in-register.
// ---------------------------------------------------------------------------
__global__ __launch_bounds__(256) void attn_rel(const u16* __restrict__ qtd,
                                                const u16* __restrict__ qdt,
                                                const u16* __restrict__ relk,
                                                u16* __restrict__ outa) {
  // LDS: [0,32768) K/V double buffers (K 8KB + VT 8KB per buf)
  //      [0,10240) aliased: rel_k_emb padded to [80][64] bf16 (prologue only)
  //      [32768,40960) qrel [64][64] bf16 (rel 0..63; rel=64 kept in bhi reg)
  //      [40960,49152) P per-wave [16][128B] bf16, XOR-swizzled
  __shared__ __align__(16) char smem[49152];
  const int tid = threadIdx.x;
  const int lane = tid & 63, w = tid >> 6;
  const int g = lane >> 4, l15 = lane & 15;
  // XCD-aware remap: lin%8 = XCD; 4 consecutive bh per XCD (K/V fits 4MB L2).
  int lin = blockIdx.y * 32 + blockIdx.x;
  int sidx = lin >> 3;
  const int bh = (lin & 7) * 4 + (sidx & 3);
  const int q0 = (sidx >> 2) * 64;
  const int q0w = q0 + w * 16;
  u16* qrelb = (u16*)(smem + 32768);
  char* Pbuf = smem + 40960 + w * 2048;

  // Q fragments (B-operand): row q = l15, d = g*8 (+32c); prescale SCALE*log2e
  short8 qa[2];
  {
    size_t rowoff = ((size_t)bh * 2048 + q0w + l15) * 64;
    qa[0] = *(const short8*)(qtd + rowoff + g * 8);
    qa[1] = *(const short8*)(qtd + rowoff + g * 8 + 32);
    const float QS = 0.18033688f;  // 0.125 * log2(e)
#pragma unroll
    for (int c = 0; c < 2; ++c)
#pragma unroll
      for (int e = 0; e < 8; ++e)
        qa[c][e] = (short)bf16bits(bf16tof((u16)qa[c][e]) * QS);
  }

  // Stage rel_k_emb (65x64 bf16 = 520 chunks), zero-pad rows 65..79
  for (int c = tid; c < 520; c += 256)
    *(uint4*)(smem + c * 16) = *(const uint4*)((const char*)relk + c * 16);
  for (int c = 520 + tid; c < 640; c += 256) {
    uint4 z; z.x = 0u; z.y = 0u; z.z = 0u; z.w = 0u;
    *(uint4*)(smem + c * 16) = z;
  }
  __syncthreads();

  // qrel (swapped): aq[t] = D[rel=t*16+4g+r][q=l15]
  f32x4 aq[5] = {};
#pragma unroll
  for (int t = 0; t < 5; ++t)
#pragma unroll
    for (int c = 0; c < 2; ++c) {
      short8 rb = *(const short8*)(smem + ((t * 16 + l15) * 64 + g * 8 + c * 32) * 2);
      aq[t] = MFMA16(rb, qa[c], aq[t]);
    }
  // per-lane bias for own q-row l15: rel=64 at (g=0, reg 0, col=l15) of aq[4];
  // rel=0 at same coords of aq[0].
  float bhi = __shfl(aq[4][0], l15);
  float blo = __shfl(aq[0][0], l15);
  // store rel 0..63 into qrelb[q][rel]  (q row-in-block = w*16+l15)
#pragma unroll
  for (int t = 0; t < 4; ++t)
#pragma unroll
    for (int r = 0; r < 4; ++r)
      qrelb[(w * 16 + l15) * 64 + t * 16 + 4 * g + r] = bf16bits(aq[t][r]);
  __syncthreads();  // rel region reads done before K staging overwrites it

  auto stageKV = [&](int kv0, int buf) {
    char* Kb = smem + buf * 16384;
    char* Vb = Kb + 8192;
    int sub = lane >> 3, chunk = lane & 7;
#pragma unroll
    for (int i = 0; i < 2; ++i) {
      int rloc = (w * 2 + i) * 8 + sub;  // 0..63 ; rloc&7 == sub
      int swz = (chunk * 16) ^ ((rloc & 7) << 4);
      gload16((const char*)qtd + ((size_t)bh * 2048 + kv0 + rloc) * 128 + swz,
              Kb + (w * 2 + i) * 1024);
      gload16((const char*)qdt + ((size_t)bh * 64 + rloc) * 4096 + kv0 * 2 + swz,
              Vb + (w * 2 + i) * 1024);
    }
  };

  f32x4 aco[4] = {};
  float lrow = 0.f;  // partial row-sum for q = l15 (own k-slices)

  stageKV(0, 0);
  __syncthreads();
  for (int ti = 0; ti < 32; ++ti) {
    int buf = ti & 1;
    int kv0 = ti * 64;
    if (ti + 1 < 32) stageKV(kv0 + 64, buf ^ 1);
    const char* Kb = smem + buf * 16384;
    const char* Vb = Kb + 8192;

    // bias as accumulator init; s layout D[k=jt*16+4g+r][q=l15]
    f32x4 s[4];
    bool farL = (q0w - (kv0 + 63)) >= 32;   // all i-j >= 32  -> bhi
    bool farR = (q0w + 15 - kv0) <= -32;    // all i-j <= -32 -> blo
    if (farL || farR) {
      float bv = farL ? bhi : blo;
      f32x4 binit = {bv, bv, bv, bv};
#pragma unroll
      for (int jt = 0; jt < 4; ++jt) s[jt] = binit;
    } else {
#pragma unroll
      for (int jt = 0; jt < 4; ++jt)
#pragma unroll
        for (int r = 0; r < 4; ++r) {
          int dd = (q0w + l15) - (kv0 + jt * 16 + 4 * g + r);
          int idx = dd < -32 ? 0 : (dd > 31 ? 63 : dd + 32);
          float tb = bf16tof(qrelb[(w * 16 + l15) * 64 + idx]);
          s[jt][r] = dd >= 32 ? bhi : tb;
        }
    }

    // S^T = K Q^T + bias  (Q carries SCALE*log2e)
#pragma unroll
    for (int jt = 0; jt < 4; ++jt) {
      int jloc = jt * 16 + l15;
      int sw = (jloc & 7) << 4;
#pragma unroll
      for (int c = 0; c < 2; ++c) {
        short8 kb = *(const short8*)(Kb + ((jloc * 128 + g * 16 + c * 64) ^ sw));
        s[jt] = MFMA16(kb, qa[c], s[jt]);
      }
    }

    // P = 2^S (unnormalized); lane owns q=l15, k = jt*16+4g+r
    // store P[q][k] to per-wave swizzled Pbuf: one b64 per jt
    float lsum = 0.f;
    int psw = (l15 & 7) << 4;
#pragma unroll
    for (int jt = 0; jt < 4; ++jt) {
      float p0 = exp2fast(s[jt][0]);
      float p1 = exp2fast(s[jt][1]);
      float p2 = exp2fast(s[jt][2]);
      float p3 = exp2fast(s[jt][3]);
      lsum += (p0 + p1) + (p2 + p3);
      union { float f; unsigned u; } c0, c1, c2, c3;
      c0.f = p0; c1.f = p1; c2.f = p2; c3.f = p3;
      uint2 wv;
      wv.x = (c0.u >> 16) | (c1.u & 0xFFFF0000u);
      wv.y = (c2.u >> 16) | (c3.u & 0xFFFF0000u);
      *(uint2*)(Pbuf + ((l15 * 128 + jt * 32 + g * 8) ^ psw)) = wv;
    }
    lrow += lsum;

    // O += P V   (A = P rows from Pbuf; B = V^T tile)
    short8 pa0 = *(const short8*)(Pbuf + ((l15 * 128 + g * 16) ^ psw));
    short8 pa1 = *(const short8*)(Pbuf + ((l15 * 128 + g * 16 + 64) ^ psw));
#pragma unroll
    for (int dt = 0; dt < 4; ++dt) {
      int dloc = dt * 16 + l15;
      int sw = (dloc & 7) << 4;
      short8 vb0 = *(const short8*)(Vb + ((dloc * 128 + g * 16) ^ sw));
      short8 vb1 = *(const short8*)(Vb + ((dloc * 128 + g * 16 + 64) ^ sw));
      aco[dt] = MFMA16(pa0, vb0, aco[dt]);
      aco[dt] = MFMA16(pa1, vb1, aco[dt]);
    }
    __syncthreads();
  }

  // finish row sums: reduce partials across the 4 g-lanes of each l15
  lrow += __shfl_xor(lrow, 16);
  lrow += __shfl_xor(lrow, 32);

  // epilogue: O/l -> [B,T,H,64]   (aco: q=4g+r, d=l15+16dt)
  int b = bh >> 4, h = bh & 15;
#pragma unroll
  for (int r = 0; r < 4; ++r) {
    float lr = __shfl(lrow, 4 * g + r);  // lanes 0..15 hold l(q=l15)
    float rl = 1.0f / lr;
    int t = q0w + 4 * g + r;
    size_t base = ((size_t)(b * 2048 + t) * 16 + h) * 64;
#pragma unroll
    for (int dt = 0; dt < 4; ++dt)
      outa[base + dt * 16 + l15] = bf16bits(aco[dt][r] * rl);
  }
}

// ---------------------------------------------------------------------------
extern "C" void kernel_launch(void* const* d_in, const int* in_sizes, int n_in,
                              void* d_out, int out_size, void* d_ws, size_t ws_size,
                              hipStream_t stream) {
  const float* x    = (const float*)d_in[0];   // [2,2048,1024] f32
  const float* Wq   = (const float*)d_in[1];   // [1024,1024] f32
  const float* Wo   = (const float*)d_in[2];   // [1024,1024] f32
  const float* relk = (const float*)d_in[3];   // [65,64] f32
  float* out = (float*)d_out;                  // [2,2048,1024] f32

  u16* q_td   = (u16*)d_ws;                    // 4,194,304  [B,H,T,64] bf16
  u16* q_dt   = q_td + 4194304;                // 4,194,304  [B,H,64,T] bf16
  u16* x_bf   = q_dt + 4194304;                // 4,194,304  (aliased as attn later)
  u16* wq_bf  = x_bf + 4194304;                // 1,048,576
  u16* wo_bf  = wq_bf + 1048576;               // 1,048,576
  u16* rel_bf = wo_bf + 1048576;               // 4,160
  u16* attn   = x_bf;                          // alias: x_bf consumed by gemm1

  // 1) f32 -> bf16 for all inputs
  cvt4<<<dim3(2048, 4), 256, 0, stream>>>(x, x_bf, 4194304,
                                          Wq, wq_bf, 1048576,
                                          Wo, wo_bf, 1048576,
                                          relk, rel_bf, 4160);
  // 2) q = x @ Wq^T  (dual-layout bf16 store; 128x128 tiles, BK=64, 8 waves)
  gemm_bt<1><<<dim3(8, 32), 512, 0, stream>>>(x_bf, wq_bf, q_td, q_dt, nullptr,
                                              4096, 1024, 1024);
  // 3) flash attention with relative bias (FROZEN round-6 passing kernel)
  attn_rel<<<dim3(32, 32), 256, 0, stream>>>(q_td, q_dt, rel_bf, attn);
  // 4) out = attn @ Wo^T  (f32 store; 128x128 tiles, BK=64, 8 waves)
  gemm_bt<0><<<dim3(8, 32), 512, 0, stream>>>(attn, wo_bf, nullptr, nullptr, out,
                                              4096, 1024, 1024);
}

// Round 14
// 112.923 us; speedup vs baseline: 1.0569x; 1.0225x over previous
//
#include <hip/hip_runtime.h>
#include <stdint.h>

typedef unsigned short u16;
typedef __attribute__((ext_vector_type(8))) short short8;
typedef __attribute__((ext_vector_type(4))) float f32x4;

#define MFMA16(a, b, c) __builtin_amdgcn_mfma_f32_16x16x32_bf16((a), (b), (c), 0, 0, 0)

__device__ __forceinline__ void gload16(const void* g, void* l) {
  __builtin_amdgcn_global_load_lds((const __attribute__((address_space(1))) void*)g,
                                   (__attribute__((address_space(3))) void*)l, 16, 0, 0);
}

__device__ __forceinline__ u16 bf16bits(float f) {
  union { float f; unsigned u; } x; x.f = f;
  unsigned r = x.u + 0x7fffu + ((x.u >> 16) & 1u);
  return (u16)(r >> 16);
}

__device__ __forceinline__ float bf16tof(u16 b) {
  union { unsigned u; float f; } x; x.u = ((unsigned)b) << 16;
  return x.f;
}

__device__ __forceinline__ float exp2fast(float x) {
  float r;
  asm("v_exp_f32 %0, %1" : "=v"(r) : "v"(x));
  return r;
}

// ---------------------------------------------------------------------------
// f32 -> bf16 conversion, 4 arrays in one launch (blockIdx.y selects array).
// ---------------------------------------------------------------------------
__global__ __launch_bounds__(256) void cvt4(const float* __restrict__ s0, u16* __restrict__ d0, int n0,
                                            const float* __restrict__ s1, u16* __restrict__ d1, int n1,
                                            const float* __restrict__ s2, u16* __restrict__ d2, int n2,
                                            const float* __restrict__ s3, u16* __restrict__ d3, int n3) {
  const float* s; u16* d; int n;
  switch (blockIdx.y) {
    case 0:  s = s0; d = d0; n = n0; break;
    case 1:  s = s1; d = d1; n = n1; break;
    case 2:  s = s2; d = d2; n = n2; break;
    default: s = s3; d = d3; n = n3; break;
  }
  int stride = gridDim.x * blockDim.x;
  for (int i = blockIdx.x * blockDim.x + threadIdx.x; i * 8 < n; i += stride) {
    float4 a = ((const float4*)s)[i * 2];
    float4 b = ((const float4*)s)[i * 2 + 1];
    union { u16 u[8]; uint4 v; } pk;
    pk.u[0] = bf16bits(a.x); pk.u[1] = bf16bits(a.y);
    pk.u[2] = bf16bits(a.z); pk.u[3] = bf16bits(a.w);
    pk.u[4] = bf16bits(b.x); pk.u[5] = bf16bits(b.y);
    pk.u[6] = bf16bits(b.z); pk.u[7] = bf16bits(b.w);
    ((uint4*)d)[i] = pk.v;
  }
}

// ---------------------------------------------------------------------------
// GEMM: C[M,N] = A[M,K] @ B[N,K]^T   (bf16 in, K contiguous — "BT" layout)
// BM=128, BN=128, BK=64. 8 waves in 2x4; wave tile 64x32 (acc[4][2]).
// Triple-buffered staging with counted vmcnt(4): loads for tile kk+2 stay
// in flight across the (raw) barrier — no full drain per K-step.
// XCD-grouped tile swizzle: all 8 N-tiles of an A-stripe share lin%8 (XCD),
// so the A-tile is read once into that XCD's L2. Grid must be (8, M/128).
// LDS rows 128B -> attn-proven XOR swizzle (inverse-swz source, XOR read).
// EPI=0: f32 store.  EPI=1: dual bf16 store q_td / q_dt.
// ---------------------------------------------------------------------------
template <int EPI>
__global__ __launch_bounds__(512) void gemm_bt(const u16* __restrict__ A,
                                               const u16* __restrict__ Bw,
                                               u16* __restrict__ out0,
                                               u16* __restrict__ out1,
                                               float* __restrict__ outf,
                                               int M, int N, int K) {
  __shared__ __align__(16) char smem[3 * 32768];  // per buf: A 16K + B 16K
  const int tid = threadIdx.x;
  const int lane = tid & 63, w = tid >> 6;   // w in [0,8)
  const int g = lane >> 4, l15 = lane & 15;
  // XCD-grouped bijective remap (grid fixed at 8 x 32):
  //   c = lin&7 (XCD under round-robin dispatch); ytile = c + 8*(sidx>>3)
  //   -> the 8 xtiles sharing A-stripe ytile all live on XCD ytile&7.
  int lin = blockIdx.y * 8 + blockIdx.x;     // [0,256)
  int sidx = lin >> 3;                       // [0,32)
  int ytile = (lin & 7) + 8 * (sidx >> 3);   // [0,32)
  int xtile = sidx & 7;                      // [0,8)
  const int m0 = ytile * 128, n0 = xtile * 128;
  const int wm = w >> 2, wn = w & 3;
  const int NK = K >> 6;                     // 16
  const size_t K2 = (size_t)K * 2;
  f32x4 acc[4][2] = {};

  auto stage = [&](int kk, int buf) {
    char* Ab_l = smem + buf * 32768;
    char* Bb_l = smem + buf * 32768 + 16384;
    int sub = lane >> 3, chunk = lane & 7;
    const char* Ab = (const char*)A + ((size_t)m0 * K + kk * 64) * 2;
    const char* Bb = (const char*)Bw + ((size_t)n0 * K + kk * 64) * 2;
#pragma unroll
    for (int i = 0; i < 2; ++i) {
      int row = i * 64 + w * 8 + sub;              // 0..127 ; row&7 == sub
      int swz = (chunk * 16) ^ ((row & 7) << 4);   // inverse-swizzled source
      gload16(Ab + (size_t)row * K2 + swz, Ab_l + i * 8192 + w * 1024);
      gload16(Bb + (size_t)row * K2 + swz, Bb_l + i * 8192 + w * 1024);
    }
  };

  // prologue: 2 tiles in flight; wait for tile 0 only (vmcnt(4) leaves
  // tile 1's 4 loads outstanding across the barrier).
  stage(0, 0);
  stage(1, 1);
  asm volatile("s_waitcnt vmcnt(4)" ::: "memory");
  __builtin_amdgcn_s_barrier();

  int buf = 0;
  for (int kk = 0; kk < NK; ++kk) {
    int nbuf = buf + 1 == 3 ? 0 : buf + 1;
    int nnbuf = nbuf + 1 == 3 ? 0 : nbuf + 1;
    if (kk + 2 < NK) stage(kk + 2, nnbuf);
    const char* Abuf = smem + buf * 32768;
    const char* Bbuf = Abuf + 16384;
    int sw = (l15 & 7) << 4;
    short8 af[4][2], bfr[2][2];
#pragma unroll
    for (int mt = 0; mt < 4; ++mt) {
      int row = wm * 64 + mt * 16 + l15;
#pragma unroll
      for (int c = 0; c < 2; ++c)
        af[mt][c] = *(const short8*)(Abuf + ((row * 128 + g * 16 + c * 64) ^ sw));
    }
#pragma unroll
    for (int nt = 0; nt < 2; ++nt) {
      int row = wn * 32 + nt * 16 + l15;
#pragma unroll
      for (int c = 0; c < 2; ++c)
        bfr[nt][c] = *(const short8*)(Bbuf + ((row * 128 + g * 16 + c * 64) ^ sw));
    }
#pragma unroll
    for (int c = 0; c < 2; ++c)
#pragma unroll
      for (int mt = 0; mt < 4; ++mt)
#pragma unroll
        for (int nt = 0; nt < 2; ++nt)
          acc[mt][nt] = MFMA16(af[mt][c], bfr[nt][c], acc[mt][nt]);
    if (kk + 1 < NK) {
      // tile kk+1 must be resident; tile kk+2 (4 loads) may stay in flight
      if (kk + 2 < NK) asm volatile("s_waitcnt vmcnt(4)" ::: "memory");
      else             asm volatile("s_waitcnt vmcnt(0)" ::: "memory");
      __builtin_amdgcn_s_barrier();
    }
    buf = nbuf;
  }

#pragma unroll
  for (int mt = 0; mt < 4; ++mt)
#pragma unroll
    for (int nt = 0; nt < 2; ++nt) {
      int n = n0 + wn * 32 + nt * 16 + l15;
      int mbase = m0 + wm * 64 + mt * 16 + 4 * g;
      if constexpr (EPI == 0) {
#pragma unroll
        for (int r = 0; r < 4; ++r)
          outf[(size_t)(mbase + r) * N + n] = acc[mt][nt][r];
      } else {
        int b = mbase >> 11, t = mbase & 2047;
        int h = n >> 6, d = n & 63;
        size_t bhb = (size_t)(b * 16 + h) * (2048 * 64);
        union { u16 u[4]; uint2 v; } pk;
#pragma unroll
        for (int r = 0; r < 4; ++r) {
          u16 uu = bf16bits(acc[mt][nt][r]);
          out0[bhb + (size_t)(t + r) * 64 + d] = uu;  // [B,H,T,64]
          pk.u[r] = uu;
        }
        *(uint2*)(out1 + bhb + (size_t)d * 2048 + t) = pk.v;  // [B,H,64,T]
      }
    }
}

// ---------------------------------------------------------------------------
// Flash attention with relative-position bias. K=V=Q (bf16).
// VERBATIM round-6 passing kernel (FROZEN — 5 structurally-equivalent edits
// failed; do not modify). Swapped QK^T (A=K, B=Q); lane holds
// P[q=l15][k=16jt+4g+r]; P via per-wave XOR-swizzled LDS buffer; no-max
// exp2 softmax; row sums in-register.
// ---------------------------------------------------------------------------
__global__ __launch_bounds__(256) void attn_rel(const u16* __restrict__ qtd,
                                                const u16* __restrict__ qdt,
                                                const u16* __restrict__ relk,
                                                u16* __restrict__ outa) {
  // LDS: [0,32768) K/V double buffers (K 8KB + VT 8KB per buf)
  //      [0,10240) aliased: rel_k_emb padded to [80][64] bf16 (prologue only)
  //      [32768,40960) qrel [64][64] bf16 (rel 0..63; rel=64 kept in bhi reg)
  //      [40960,49152) P per-wave [16][128B] bf16, XOR-swizzled
  __shared__ __align__(16) char smem[49152];
  const int tid = threadIdx.x;
  const int lane = tid & 63, w = tid >> 6;
  const int g = lane >> 4, l15 = lane & 15;
  // XCD-aware remap: lin%8 = XCD; 4 consecutive bh per XCD (K/V fits 4MB L2).
  int lin = blockIdx.y * 32 + blockIdx.x;
  int sidx = lin >> 3;
  const int bh = (lin & 7) * 4 + (sidx & 3);
  const int q0 = (sidx >> 2) * 64;
  const int q0w = q0 + w * 16;
  u16* qrelb = (u16*)(smem + 32768);
  char* Pbuf = smem + 40960 + w * 2048;

  // Q fragments (B-operand): row q = l15, d = g*8 (+32c); prescale SCALE*log2e
  short8 qa[2];
  {
    size_t rowoff = ((size_t)bh * 2048 + q0w + l15) * 64;
    qa[0] = *(const short8*)(qtd + rowoff + g * 8);
    qa[1] = *(const short8*)(qtd + rowoff + g * 8 + 32);
    const float QS = 0.18033688f;  // 0.125 * log2(e)
#pragma unroll
    for (int c = 0; c < 2; ++c)
#pragma unroll
      for (int e = 0; e < 8; ++e)
        qa[c][e] = (short)bf16bits(bf16tof((u16)qa[c][e]) * QS);
  }

  // Stage rel_k_emb (65x64 bf16 = 520 chunks), zero-pad rows 65..79
  for (int c = tid; c < 520; c += 256)
    *(uint4*)(smem + c * 16) = *(const uint4*)((const char*)relk + c * 16);
  for (int c = 520 + tid; c < 640; c += 256) {
    uint4 z; z.x = 0u; z.y = 0u; z.z = 0u; z.w = 0u;
    *(uint4*)(smem + c * 16) = z;
  }
  __syncthreads();

  // qrel (swapped): aq[t] = D[rel=t*16+4g+r][q=l15]
  f32x4 aq[5] = {};
#pragma unroll
  for (int t = 0; t < 5; ++t)
#pragma unroll
    for (int c = 0; c < 2; ++c) {
      short8 rb = *(const short8*)(smem + ((t * 16 + l15) * 64 + g * 8 + c * 32) * 2);
      aq[t] = MFMA16(rb, qa[c], aq[t]);
    }
  // per-lane bias for own q-row l15: rel=64 at (g=0, reg 0, col=l15) of aq[4];
  // rel=0 at same coords of aq[0].
  float bhi = __shfl(aq[4][0], l15);
  float blo = __shfl(aq[0][0], l15);
  // store rel 0..63 into qrelb[q][rel]  (q row-in-block = w*16+l15)
#pragma unroll
  for (int t = 0; t < 4; ++t)
#pragma unroll
    for (int r = 0; r < 4; ++r)
      qrelb[(w * 16 + l15) * 64 + t * 16 + 4 * g + r] = bf16bits(aq[t][r]);
  __syncthreads();  // rel region reads done before K staging overwrites it

  auto stageKV = [&](int kv0, int buf) {
    char* Kb = smem + buf * 16384;
    char* Vb = Kb + 8192;
    int sub = lane >> 3, chunk = lane & 7;
#pragma unroll
    for (int i = 0; i < 2; ++i) {
      int rloc = (w * 2 + i) * 8 + sub;  // 0..63 ; rloc&7 == sub
      int swz = (chunk * 16) ^ ((rloc & 7) << 4);
      gload16((const char*)qtd + ((size_t)bh * 2048 + kv0 + rloc) * 128 + swz,
              Kb + (w * 2 + i) * 1024);
      gload16((const char*)qdt + ((size_t)bh * 64 + rloc) * 4096 + kv0 * 2 + swz,
              Vb + (w * 2 + i) * 1024);
    }
  };

  f32x4 aco[4] = {};
  float lrow = 0.f;  // partial row-sum for q = l15 (own k-slices)

  stageKV(0, 0);
  __syncthreads();
  for (int ti = 0; ti < 32; ++ti) {
    int buf = ti & 1;
    int kv0 = ti * 64;
    if (ti + 1 < 32) stageKV(kv0 + 64, buf ^ 1);
    const char* Kb = smem + buf * 16384;
    const char* Vb = Kb + 8192;

    // bias as accumulator init; s layout D[k=jt*16+4g+r][q=l15]
    f32x4 s[4];
    bool farL = (q0w - (kv0 + 63)) >= 32;   // all i-j >= 32  -> bhi
    bool farR = (q0w + 15 - kv0) <= -32;    // all i-j <= -32 -> blo
    if (farL || farR) {
      float bv = farL ? bhi : blo;
      f32x4 binit = {bv, bv, bv, bv};
#pragma unroll
      for (int jt = 0; jt < 4; ++jt) s[jt] = binit;
    } else {
#pragma unroll
      for (int jt = 0; jt < 4; ++jt)
#pragma unroll
        for (int r = 0; r < 4; ++r) {
          int dd = (q0w + l15) - (kv0 + jt * 16 + 4 * g + r);
          int idx = dd < -32 ? 0 : (dd > 31 ? 63 : dd + 32);
          float tb = bf16tof(qrelb[(w * 16 + l15) * 64 + idx]);
          s[jt][r] = dd >= 32 ? bhi : tb;
        }
    }

    // S^T = K Q^T + bias  (Q carries SCALE*log2e)
#pragma unroll
    for (int jt = 0; jt < 4; ++jt) {
      int jloc = jt * 16 + l15;
      int sw = (jloc & 7) << 4;
#pragma unroll
      for (int c = 0; c < 2; ++c) {
        short8 kb = *(const short8*)(Kb + ((jloc * 128 + g * 16 + c * 64) ^ sw));
        s[jt] = MFMA16(kb, qa[c], s[jt]);
      }
    }

    // P = 2^S (unnormalized); lane owns q=l15, k = jt*16+4g+r
    // store P[q][k] to per-wave swizzled Pbuf: one b64 per jt
    float lsum = 0.f;
    int psw = (l15 & 7) << 4;
#pragma unroll
    for (int jt = 0; jt < 4; ++jt) {
      float p0 = exp2fast(s[jt][0]);
      float p1 = exp2fast(s[jt][1]);
      float p2 = exp2fast(s[jt][2]);
      float p3 = exp2fast(s[jt][3]);
      lsum += (p0 + p1) + (p2 + p3);
      union { float f; unsigned u; } c0, c1, c2, c3;
      c0.f = p0; c1.f = p1; c2.f = p2; c3.f = p3;
      uint2 wv;
      wv.x = (c0.u >> 16) | (c1.u & 0xFFFF0000u);
      wv.y = (c2.u >> 16) | (c3.u & 0xFFFF0000u);
      *(uint2*)(Pbuf + ((l15 * 128 + jt * 32 + g * 8) ^ psw)) = wv;
    }
    lrow += lsum;

    // O += P V   (A = P rows from Pbuf; B = V^T tile)
    short8 pa0 = *(const short8*)(Pbuf + ((l15 * 128 + g * 16) ^ psw));
    short8 pa1 = *(const short8*)(Pbuf + ((l15 * 128 + g * 16 + 64) ^ psw));
#pragma unroll
    for (int dt = 0; dt < 4; ++dt) {
      int dloc = dt * 16 + l15;
      int sw = (dloc & 7) << 4;
      short8 vb0 = *(const short8*)(Vb + ((dloc * 128 + g * 16) ^ sw));
      short8 vb1 = *(const short8*)(Vb + ((dloc * 128 + g * 16 + 64) ^ sw));
      aco[dt] = MFMA16(pa0, vb0, aco[dt]);
      aco[dt] = MFMA16(pa1, vb1, aco[dt]);
    }
    __syncthreads();
  }

  // finish row sums: reduce partials across the 4 g-lanes of each l15
  lrow += __shfl_xor(lrow, 16);
  lrow += __shfl_xor(lrow, 32);

  // epilogue: O/l -> [B,T,H,64]   (aco: q=4g+r, d=l15+16dt)
  int b = bh >> 4, h = bh & 15;
#pragma unroll
  for (int r = 0; r < 4; ++r) {
    float lr = __shfl(lrow, 4 * g + r);  // lanes 0..15 hold l(q=l15)
    float rl = 1.0f / lr;
    int t = q0w + 4 * g + r;
    size_t base = ((size_t)(b * 2048 + t) * 16 + h) * 64;
#pragma unroll
    for (int dt = 0; dt < 4; ++dt)
      outa[base + dt * 16 + l15] = bf16bits(aco[dt][r] * rl);
  }
}

// ---------------------------------------------------------------------------
extern "C" void kernel_launch(void* const* d_in, const int* in_sizes, int n_in,
                              void* d_out, int out_size, void* d_ws, size_t ws_size,
                              hipStream_t stream) {
  const float* x    = (const float*)d_in[0];   // [2,2048,1024] f32
  const float* Wq   = (const float*)d_in[1];   // [1024,1024] f32
  const float* Wo   = (const float*)d_in[2];   // [1024,1024] f32
  const float* relk = (const float*)d_in[3];   // [65,64] f32
  float* out = (float*)d_out;                  // [2,2048,1024] f32

  u16* q_td   = (u16*)d_ws;                    // 4,194,304  [B,H,T,64] bf16
  u16* q_dt   = q_td + 4194304;                // 4,194,304  [B,H,64,T] bf16
  u16* x_bf   = q_dt + 4194304;                // 4,194,304  (aliased as attn later)
  u16* wq_bf  = x_bf + 4194304;                // 1,048,576
  u16* wo_bf  = wq_bf + 1048576;               // 1,048,576
  u16* rel_bf = wo_bf + 1048576;               // 4,160
  u16* attn   = x_bf;                          // alias: x_bf consumed by gemm1

  // 1) f32 -> bf16 for all inputs
  cvt4<<<dim3(2048, 4), 256, 0, stream>>>(x, x_bf, 4194304,
                                          Wq, wq_bf, 1048576,
                                          Wo, wo_bf, 1048576,
                                          relk, rel_bf, 4160);
  // 2) q = x @ Wq^T  (dual-layout bf16 store; 128x128, BK=64, 3-buf vmcnt)
  gemm_bt<1><<<dim3(8, 32), 512, 0, stream>>>(x_bf, wq_bf, q_td, q_dt, nullptr,
                                              4096, 1024, 1024);
  // 3) flash attention with relative bias (FROZEN round-6 passing kernel)
  attn_rel<<<dim3(32, 32), 256, 0, stream>>>(q_td, q_dt, rel_bf, attn);
  // 4) out = attn @ Wo^T  (f32 store; 128x128, BK=64, 3-buf vmcnt)
  gemm_bt<0><<<dim3(8, 32), 512, 0, stream>>>(attn, wo_bf, nullptr, nullptr, out,
                                              4096, 1024, 1024);
}